// Round 19
// baseline (229.587 us; speedup 1.0000x reference)
//
#include <hip/hip_runtime.h>

#define CIN 48
#define COUT 48
#define NPIX 16384  // 128*128
#define XFP 52      // XF pitch in shorts (104 B): bank conflicts 5.8M -> 0.88M (R11/R12)

typedef float f32x4 __attribute__((ext_vector_type(4)));
typedef short bf16x8 __attribute__((ext_vector_type(8)));

__device__ __forceinline__ unsigned short f2bf(float f) {
  unsigned u = __float_as_uint(f);
  unsigned r = (u + 0x7FFFu + ((u >> 16) & 1u)) >> 16;  // RNE
  return (unsigned short)r;
}

// ws layout (floats):
//   w[20736] | ar[128] | ai[128] | pad->21248 | Up[1572864] | yf[786432] | wbf64[13824]
#define OFF_UP     21248
#define OFF_YF     (OFF_UP + CIN * NPIX * 2)
#define OFF_WBF64  (OFF_YF + CIN * NPIX)

// ---------------------------------------------------------------------------
// K1: Gabor weights. f32 w[oc][i][9]; bf16 A-table wbf64[(k*48+oc)*64+i],
//     i pad [48,64) zeroed.
// ---------------------------------------------------------------------------
__global__ __launch_bounds__(256) void gabor_k(
    const float* __restrict__ freq, const float* __restrict__ theta,
    const float* __restrict__ sigma, const float* __restrict__ psi,
    const float* __restrict__ f0, const float* __restrict__ theta0,
    float* __restrict__ wout, unsigned short* __restrict__ wbf64)
{
  int idx = blockIdx.x * 256 + threadIdx.x;
  if (idx < 432 * 16) {
    wbf64[(idx >> 4) * 64 + 48 + (idx & 15)] = 0;
  }
  if (idx >= COUT * CIN * 9) return;
  int k = idx % 9;
  int oi = idx / 9;
  int oc = oi / CIN, ic = oi % CIN;
  int a = k / 3, b = k % 3;
  float Yv = (a == 0) ? -1.0f : ((a == 1) ? 0.5f : 2.0f);
  float Xv = (b == 0) ? -1.0f : ((b == 1) ? 0.5f : 2.0f);
  float th = theta[oi], sg = sigma[oi], fr = freq[oi], ps = psi[oi];
  float F0 = f0[oi], th0 = theta0[oi];
  float c = cosf(th), s = sinf(th);
  float rotx =  Xv * c + Yv * s;
  float roty = -Xv * s + Yv * c;
  float r = sqrtf(rotx * rotx + roty * roty + 0.001f);
  float denom = 2.0f * logf(sg / F0);
  float t1 = (logf(r) - logf(F0)) / denom;
  float g_rad = expf(-t1 * t1);
  float dth = th - th0;
  float g_ang = expf(-dth * dth / (2.0f * sg * sg));
  float g = g_rad * g_ang * cosf(fr * r + ps) / (6.283185307179586f * sg * sg);
  wout[idx] = g;
  wbf64[(k * 48 + oc) * 64 + ic] = f2bf(g);
}

// ---------------------------------------------------------------------------
// K2: circulant band-limit vector
// ---------------------------------------------------------------------------
__global__ void circ_k(float* __restrict__ ar, float* __restrict__ ai)
{
  int d = threadIdx.x;
  float sr = 0.f, si = 0.f;
  for (int u = 34; u < 94; ++u) {
    int m = (u * d) & 127;
    float ang = (float)m * 0.049087385212340526f;
    sr += cosf(ang);
    si += sinf(ang);
  }
  ar[d] = sr * (1.0f / 128.0f);
  ai[d] = si * (1.0f / 128.0f);
}

// ---------------------------------------------------------------------------
// K3a: row band-limit. grid (16, 48): 8 rows per block.
// ---------------------------------------------------------------------------
__global__ __launch_bounds__(256) void stage1_k(
    const float* __restrict__ x, const float* __restrict__ arr,
    const float* __restrict__ aii, float2* __restrict__ Up)
{
  __shared__ float Xs[8 * 128];
  __shared__ float ars[128], ais[128];
  int yg = blockIdx.x, i = blockIdx.y;
  int t = threadIdx.x;
  const float* Xi = x + i * NPIX + yg * 8 * 128;
  for (int p = t; p < 1024; p += 256) Xs[p] = Xi[p];
  if (t < 128) { ars[t] = arr[t]; ais[t] = aii[t]; }
  __syncthreads();
  int j = t & 127;
  int ysl = t >> 7;
  float accr[4], acci[4];
#pragma unroll
  for (int yy = 0; yy < 4; ++yy) { accr[yy] = 0.f; acci[yy] = 0.f; }
  for (int xx = 0; xx < 128; ++xx) {
    float tr = ars[(j - xx) & 127];
    float ti = ais[(j - xx) & 127];
#pragma unroll
    for (int yy = 0; yy < 4; ++yy) {
      float xv = Xs[(ysl * 4 + yy) * 128 + xx];
      accr[yy] += xv * tr;
      acci[yy] += xv * ti;
    }
  }
  float2* UpI = Up + i * NPIX;
  int ybase = yg * 8 + ysl * 4;
#pragma unroll
  for (int yy = 0; yy < 4; ++yy)
    UpI[(ybase + yy) * 128 + j] = make_float2(accr[yy], acci[yy]);
}

// ---------------------------------------------------------------------------
// K3b: column band-limit. grid (16, 48): 8 cols per block. f32 output.
// ---------------------------------------------------------------------------
__global__ __launch_bounds__(256) void stage2_k(
    const float2* __restrict__ Up, const float* __restrict__ arr,
    const float* __restrict__ aii, float* __restrict__ yf)
{
  __shared__ float2 Us[128 * 8];
  __shared__ float ars[128], ais[128];
  int jg = blockIdx.x, i = blockIdx.y;
  int t = threadIdx.x;
  const float2* UpI = Up + i * NPIX;
  for (int p = t; p < 1024; p += 256) {
    int y = p >> 3, jj = p & 7;
    Us[p] = UpI[y * 128 + jg * 8 + jj];
  }
  if (t < 128) { ars[t] = arr[t]; ais[t] = aii[t]; }
  __syncthreads();
  int yp = t & 127;
  int xsl = t >> 7;
  float acc[4];
#pragma unroll
  for (int xx = 0; xx < 4; ++xx) acc[xx] = 0.f;
  for (int y = 0; y < 128; ++y) {
    float tr = ars[(yp - y) & 127];
    float ti = ais[(yp - y) & 127];
#pragma unroll
    for (int xx = 0; xx < 4; ++xx) {
      float2 u = Us[y * 8 + xsl * 4 + xx];
      acc[xx] += u.x * tr - u.y * ti;
    }
  }
  float* yfI = yf + i * NPIX;
  int xb = jg * 8 + xsl * 4;
#pragma unroll
  for (int xx = 0; xx < 4; ++xx)
    yfI[yp * 128 + xb + xx] = acc[xx];
}

// ---------------------------------------------------------------------------
// K4: fused stencil + MFMA GEMM, 512 threads (8 waves) at (512,2).
//  R11's (512,4) capped regs at 48 -> spill; (512,2) caps ~256 -> safe.
//  Per-thread live sets SHRINK vs 256-thread variant: phase 1 = ONE task
//  (~55 live, half the serial chain), phase 2 = 2 rows/wave (acc 24 AGPR).
//  LDS 33.7 KB -> 2 blocks/CU = 16 waves/CU (50% occ vs 30.5%).
//  NaN invariant: pad [48,52) + tail zeroed; B1 spill -> next row's i<16 x
//  A-cols 48..63 = 0, or row 323 -> zeroed tail.
//  Interior tiles (x0,y0 in [16,96]) skip all bounds checks (wave-uniform).
// ---------------------------------------------------------------------------
__global__ __launch_bounds__(512, 2) void conv2_k(
    const float* __restrict__ yf, const float* __restrict__ wts,
    const unsigned short* __restrict__ wbf64, float* __restrict__ out)
{
  __shared__ __align__(16) short XF[324 * XFP + 16];

  int o  = blockIdx.z;
  int y0 = blockIdx.y * 16, x0 = blockIdx.x * 16;
  int tid = threadIdx.x;

  // phase 0: zero per-row pad shorts [48,52) and tail (NaN invariant)
  for (int p = tid; p < 324; p += 512)
    *(uint2*)(XF + p * XFP + 48) = make_uint2(0u, 0u);
  if (tid < 16) XF[324 * XFP + tid] = 0;

  // phase 1: xf(y,x) = sum_{dy,dx in 0..2} w[dy,dx] * yf((y-dy)&127,(x-dx)&127)
  // 480 tasks, ONE per thread (tid < 480): i = s/10, sp = (s%10)%5,
  // half = (s%10)/5; rows rr in [9*half, 9*half+9); px cols 4sp+j (<18).
  bool inter = (y0 >= 16) && (y0 <= 96) && (x0 >= 16) && (x0 <= 96);
  if (tid < 480) {
    int s = tid;
    int i = s / 10, r10 = s - i * 10;
    int sp = r10 % 5, half = r10 / 5;
    const float* Wp = wts + (o * CIN + i) * 9;
    float W0 = Wp[0], W1 = Wp[1], W2 = Wp[2], W3 = Wp[3], W4 = Wp[4],
          W5 = Wp[5], W6 = Wp[6], W7 = Wp[7], W8 = Wp[8];
    const float* yfp = yf + i * NPIX;
    int cb = (x0 - 4 + 4 * sp) & 127;   // mult of 4 -> float4 aligned, wrap-safe
    int rbase = half * 9;
    float Ra[8], Rb[8], Rc[8];

#define LOADROW(dst, ry) { \
    const float* rp_ = yfp + (((ry) & 127) << 7); \
    float4 q0_ = *(const float4*)(rp_ + cb); \
    float4 q1_ = *(const float4*)(rp_ + ((cb + 4) & 127)); \
    dst[0]=q0_.x; dst[1]=q0_.y; dst[2]=q0_.z; dst[3]=q0_.w; \
    dst[4]=q1_.x; dst[5]=q1_.y; dst[6]=q1_.z; dst[7]=q1_.w; }

#define EMIT(rr, R2_, R1_, R0_, CHK) { \
    int y_ = y0 - 1 + (rr); \
    _Pragma("unroll") \
    for (int j = 0; j < 4; ++j) { \
      int cidx_ = 4 * sp + j; \
      if (cidx_ < 18) { \
        float v_ = W0 * R0_[j + 3] + W1 * R0_[j + 2] + W2 * R0_[j + 1] \
                 + W3 * R1_[j + 3] + W4 * R1_[j + 2] + W5 * R1_[j + 1] \
                 + W6 * R2_[j + 3] + W7 * R2_[j + 2] + W8 * R2_[j + 1]; \
        if (CHK) { \
          int xg_ = x0 - 1 + cidx_; \
          if (!((y_ >= 0) && (y_ < 128) && (xg_ >= 0) && (xg_ < 128))) v_ = 0.f; \
        } \
        XF[((rr) * 18 + cidx_) * XFP + i] = (short)f2bf(v_); \
      } } }

#define PH1LOOP(CHK) { \
    LOADROW(Ra, y0 - 3 + rbase) \
    LOADROW(Rb, y0 - 2 + rbase) \
    _Pragma("unroll") \
    for (int rr0 = 0; rr0 < 9; rr0 += 3) { \
      int rr = rbase + rr0; \
      LOADROW(Rc, y0 - 1 + rr)  EMIT(rr,     Ra, Rb, Rc, CHK) \
      LOADROW(Ra, y0 + rr)      EMIT(rr + 1, Rb, Rc, Ra, CHK) \
      LOADROW(Rb, y0 + 1 + rr)  EMIT(rr + 2, Rc, Ra, Rb, CHK) \
    } }

    if (inter) PH1LOOP(0) else PH1LOOP(1)

#undef LOADROW
#undef EMIT
#undef PH1LOOP
  }
  __syncthreads();

  // phase 2: MFMA GEMM, 8 waves x 2 rows, A double-buffered
  int wv = tid >> 6, lane = tid & 63;
  int tx = lane & 15, gq = lane >> 4;
  f32x4 acc[2][3];
#pragma unroll
  for (int nn = 0; nn < 2; ++nn)
#pragma unroll
    for (int m = 0; m < 3; ++m) acc[nn][m] = (f32x4){0.f, 0.f, 0.f, 0.f};

  const unsigned short* abase = wbf64 + (tx)*64;
  bf16x8 Ac0[3], Ac1[3], An0[3], An1[3];
#pragma unroll
  for (int m = 0; m < 3; ++m) {
    const unsigned short* ap = abase + (m * 16) * 64;
    Ac0[m] = *(const bf16x8*)(ap + gq * 8);
    Ac1[m] = *(const bf16x8*)(ap + 32 + gq * 8);
  }

  for (int k = 0; k < 9; ++k) {
    if (k < 8) {
#pragma unroll
      for (int m = 0; m < 3; ++m) {
        const unsigned short* ap = abase + ((k + 1) * 48 + m * 16) * 64;
        An0[m] = *(const bf16x8*)(ap + gq * 8);
        An1[m] = *(const bf16x8*)(ap + 32 + gq * 8);
      }
    }
    int dy = k / 3, dx = k - dy * 3;
#pragma unroll
    for (int nn = 0; nn < 2; ++nn) {
      int n = wv * 2 + nn;   // output y-row within 16x16 tile
      const short* bp = XF + ((n + dy) * 18 + tx + dx) * XFP;
      bf16x8 B0 = *(const bf16x8*)(bp + gq * 8);
      bf16x8 B1 = *(const bf16x8*)(bp + 32 + gq * 8);  // pad/next-row, A=0 there
#pragma unroll
      for (int m = 0; m < 3; ++m) {
        acc[nn][m] = __builtin_amdgcn_mfma_f32_16x16x32_bf16(Ac0[m], B0, acc[nn][m], 0, 0, 0);
        acc[nn][m] = __builtin_amdgcn_mfma_f32_16x16x32_bf16(Ac1[m], B1, acc[nn][m], 0, 0, 0);
      }
    }
#pragma unroll
    for (int m = 0; m < 3; ++m) { Ac0[m] = An0[m]; Ac1[m] = An1[m]; }
  }

  // epilogue: C frag col=lane&15 (pixel x), row=gq*4+r (oc)
#pragma unroll
  for (int nn = 0; nn < 2; ++nn) {
    int y = y0 + wv * 2 + nn;
#pragma unroll
    for (int m = 0; m < 3; ++m) {
#pragma unroll
      for (int r = 0; r < 4; ++r) {
        int oc = m * 16 + gq * 4 + r;
        out[((size_t)(o * COUT + oc) << 14) + (y << 7) + x0 + tx] = acc[nn][m][r];
      }
    }
  }
}

// ---------------------------------------------------------------------------
extern "C" void kernel_launch(void* const* d_in, const int* in_sizes, int n_in,
                              void* d_out, int out_size, void* d_ws, size_t ws_size,
                              hipStream_t stream)
{
  const float* x      = (const float*)d_in[0];
  const float* freq   = (const float*)d_in[1];
  const float* theta  = (const float*)d_in[2];
  const float* sigma  = (const float*)d_in[3];
  const float* psi    = (const float*)d_in[4];
  const float* f0     = (const float*)d_in[5];
  const float* theta0 = (const float*)d_in[6];
  float* out = (float*)d_out;
  float* ws  = (float*)d_ws;

  float*  w     = ws;
  float*  ar    = ws + 20736;
  float*  ai    = ws + 20864;
  float2* Up    = (float2*)(ws + OFF_UP);
  float*  yf    = ws + OFF_YF;
  unsigned short* wbf64 = (unsigned short*)(ws + OFF_WBF64);

  gabor_k<<<dim3(81), dim3(256), 0, stream>>>(freq, theta, sigma, psi, f0, theta0, w, wbf64);
  circ_k<<<dim3(1), dim3(128), 0, stream>>>(ar, ai);
  stage1_k<<<dim3(16, 48), dim3(256), 0, stream>>>(x, ar, ai, Up);
  stage2_k<<<dim3(16, 48), dim3(256), 0, stream>>>(Up, ar, ai, yf);
  conv2_k<<<dim3(8, 8, 48), dim3(512), 0, stream>>>(yf, w, wbf64, out);
}

// Round 20
// 176.380 us; speedup vs baseline: 1.3017x; 1.3017x over previous
//
#include <hip/hip_runtime.h>

#define CIN 48
#define COUT 48
#define NPIX 16384  // 128*128
#define XFP 52      // XF pitch in shorts (104 B): bank conflicts 5.8M -> 0.88M (R11/R12)
#define SLICE (108 * XFP + 16)   // per-wave XF slice (6 rows x 18 cols px) + zero tail

typedef float f32x4 __attribute__((ext_vector_type(4)));
typedef short bf16x8 __attribute__((ext_vector_type(8)));

__device__ __forceinline__ unsigned short f2bf(float f) {
  unsigned u = __float_as_uint(f);
  unsigned r = (u + 0x7FFFu + ((u >> 16) & 1u)) >> 16;  // RNE
  return (unsigned short)r;
}

// ws layout (floats):
//   w[20736] | ar[128] | ai[128] | pad->21248 | Up[1572864] | yf[786432] | wbf64[13824]
#define OFF_UP     21248
#define OFF_YF     (OFF_UP + CIN * NPIX * 2)
#define OFF_WBF64  (OFF_YF + CIN * NPIX)

// ---------------------------------------------------------------------------
// K1: Gabor weights. f32 w[oc][i][9]; bf16 A-table wbf64[(k*48+oc)*64+i],
//     i pad [48,64) zeroed.
// ---------------------------------------------------------------------------
__global__ __launch_bounds__(256) void gabor_k(
    const float* __restrict__ freq, const float* __restrict__ theta,
    const float* __restrict__ sigma, const float* __restrict__ psi,
    const float* __restrict__ f0, const float* __restrict__ theta0,
    float* __restrict__ wout, unsigned short* __restrict__ wbf64)
{
  int idx = blockIdx.x * 256 + threadIdx.x;
  if (idx < 432 * 16) {
    wbf64[(idx >> 4) * 64 + 48 + (idx & 15)] = 0;
  }
  if (idx >= COUT * CIN * 9) return;
  int k = idx % 9;
  int oi = idx / 9;
  int oc = oi / CIN, ic = oi % CIN;
  int a = k / 3, b = k % 3;
  float Yv = (a == 0) ? -1.0f : ((a == 1) ? 0.5f : 2.0f);
  float Xv = (b == 0) ? -1.0f : ((b == 1) ? 0.5f : 2.0f);
  float th = theta[oi], sg = sigma[oi], fr = freq[oi], ps = psi[oi];
  float F0 = f0[oi], th0 = theta0[oi];
  float c = cosf(th), s = sinf(th);
  float rotx =  Xv * c + Yv * s;
  float roty = -Xv * s + Yv * c;
  float r = sqrtf(rotx * rotx + roty * roty + 0.001f);
  float denom = 2.0f * logf(sg / F0);
  float t1 = (logf(r) - logf(F0)) / denom;
  float g_rad = expf(-t1 * t1);
  float dth = th - th0;
  float g_ang = expf(-dth * dth / (2.0f * sg * sg));
  float g = g_rad * g_ang * cosf(fr * r + ps) / (6.283185307179586f * sg * sg);
  wout[idx] = g;
  wbf64[(k * 48 + oc) * 64 + ic] = f2bf(g);
}

// ---------------------------------------------------------------------------
// K2: circulant band-limit vector
// ---------------------------------------------------------------------------
__global__ void circ_k(float* __restrict__ ar, float* __restrict__ ai)
{
  int d = threadIdx.x;
  float sr = 0.f, si = 0.f;
  for (int u = 34; u < 94; ++u) {
    int m = (u * d) & 127;
    float ang = (float)m * 0.049087385212340526f;
    sr += cosf(ang);
    si += sinf(ang);
  }
  ar[d] = sr * (1.0f / 128.0f);
  ai[d] = si * (1.0f / 128.0f);
}

// ---------------------------------------------------------------------------
// K3a: row band-limit. grid (16, 48): 8 rows per block.
// ---------------------------------------------------------------------------
__global__ __launch_bounds__(256) void stage1_k(
    const float* __restrict__ x, const float* __restrict__ arr,
    const float* __restrict__ aii, float2* __restrict__ Up)
{
  __shared__ float Xs[8 * 128];
  __shared__ float ars[128], ais[128];
  int yg = blockIdx.x, i = blockIdx.y;
  int t = threadIdx.x;
  const float* Xi = x + i * NPIX + yg * 8 * 128;
  for (int p = t; p < 1024; p += 256) Xs[p] = Xi[p];
  if (t < 128) { ars[t] = arr[t]; ais[t] = aii[t]; }
  __syncthreads();
  int j = t & 127;
  int ysl = t >> 7;
  float accr[4], acci[4];
#pragma unroll
  for (int yy = 0; yy < 4; ++yy) { accr[yy] = 0.f; acci[yy] = 0.f; }
  for (int xx = 0; xx < 128; ++xx) {
    float tr = ars[(j - xx) & 127];
    float ti = ais[(j - xx) & 127];
#pragma unroll
    for (int yy = 0; yy < 4; ++yy) {
      float xv = Xs[(ysl * 4 + yy) * 128 + xx];
      accr[yy] += xv * tr;
      acci[yy] += xv * ti;
    }
  }
  float2* UpI = Up + i * NPIX;
  int ybase = yg * 8 + ysl * 4;
#pragma unroll
  for (int yy = 0; yy < 4; ++yy)
    UpI[(ybase + yy) * 128 + j] = make_float2(accr[yy], acci[yy]);
}

// ---------------------------------------------------------------------------
// K3b: column band-limit. grid (16, 48): 8 cols per block. f32 output.
// ---------------------------------------------------------------------------
__global__ __launch_bounds__(256) void stage2_k(
    const float2* __restrict__ Up, const float* __restrict__ arr,
    const float* __restrict__ aii, float* __restrict__ yf)
{
  __shared__ float2 Us[128 * 8];
  __shared__ float ars[128], ais[128];
  int jg = blockIdx.x, i = blockIdx.y;
  int t = threadIdx.x;
  const float2* UpI = Up + i * NPIX;
  for (int p = t; p < 1024; p += 256) {
    int y = p >> 3, jj = p & 7;
    Us[p] = UpI[y * 128 + jg * 8 + jj];
  }
  if (t < 128) { ars[t] = arr[t]; ais[t] = aii[t]; }
  __syncthreads();
  int yp = t & 127;
  int xsl = t >> 7;
  float acc[4];
#pragma unroll
  for (int xx = 0; xx < 4; ++xx) acc[xx] = 0.f;
  for (int y = 0; y < 128; ++y) {
    float tr = ars[(yp - y) & 127];
    float ti = ais[(yp - y) & 127];
#pragma unroll
    for (int xx = 0; xx < 4; ++xx) {
      float2 u = Us[y * 8 + xsl * 4 + xx];
      acc[xx] += u.x * tr - u.y * ti;
    }
  }
  float* yfI = yf + i * NPIX;
  int xb = jg * 8 + xsl * 4;
#pragma unroll
  for (int xx = 0; xx < 4; ++xx)
    yfI[yp * 128 + xb + xx] = acc[xx];
}

// ---------------------------------------------------------------------------
// K4: BARRIER-FREE fused stencil + MFMA GEMM.
//  Diagnosis (R18): residency 4 blocks/CU but active occupancy 30% -- all
//  waves stall together at __syncthreads (phase-1 load chains synchronized).
//  Fix: wave wv builds ONLY the 6 XF rows its phase-2 reads (rows
//  wv*4 .. wv*4+5 of the tile's 18) in a WAVE-PRIVATE LDS slice -> zero
//  barriers; waves free-run, chains covered by other resident waves.
//  Cost: 24/18 = 1.33x redundant stencil work (+~5us VALU) -- cheap vs the
//  ~75us of synchronized stall.
//  LDS: 4 slices x (108 px x 52 + 16 zero tail) = 45 KB -> 3 blocks/CU.
//  (256,3) = proven no-spill point (84 VGPR; single-task chains ~45 live).
//  NaN invariant per slice: pads [48,52) zeroed; B1 spill reads land in
//  same-slice written data x A-cols 48..63 = 0, or the slice's zeroed tail.
//  Same-wave LDS write->read ordering: compiler emits lgkmcnt (true dep).
// ---------------------------------------------------------------------------
__global__ __launch_bounds__(256, 3) void conv2_k(
    const float* __restrict__ yf, const float* __restrict__ wts,
    const unsigned short* __restrict__ wbf64, float* __restrict__ out)
{
  __shared__ __align__(16) short XF[4 * SLICE];

  int o  = blockIdx.z;
  int y0 = blockIdx.y * 16, x0 = blockIdx.x * 16;
  int tid = threadIdx.x;
  int wv = tid >> 6, lane = tid & 63;
  short* XFw = XF + wv * SLICE;

  // phase 0 (per wave): zero pad shorts [48,52) of all 108 rows + tail
  for (int p = lane; p < 108; p += 64)
    *(uint2*)(XFw + p * XFP + 48) = make_uint2(0u, 0u);
  if (lane < 16) XFw[108 * XFP + lane] = 0;

  // phase 1 (per wave, no barrier):
  // xf(y,x) = sum_{dy,dx in 0..2} w[dy,dx] * yf((y-dy)&127,(x-dx)&127)
  // Wave's XF rows rrw 0..5 = global xf rows Ybase+rrw, Ybase = y0+wv*4-1.
  // 240 tasks: t = lane + 64q (q 0..3, t<240); i = t/5, sp = t%5;
  // task covers 6 rows x 4 px cols (cidx = 4sp+j < 18).
  int Ybase = y0 + wv * 4 - 1;
  bool inter = (y0 >= 16) && (y0 <= 96) && (x0 >= 16) && (x0 <= 96);

  for (int q = 0; q < 4; ++q) {
    int t = lane + (q << 6);
    if (t < 240) {
      int i = t / 5, sp = t - i * 5;
      const float* Wp = wts + (o * CIN + i) * 9;
      float W0 = Wp[0], W1 = Wp[1], W2 = Wp[2], W3 = Wp[3], W4 = Wp[4],
            W5 = Wp[5], W6 = Wp[6], W7 = Wp[7], W8 = Wp[8];
      const float* yfp = yf + i * NPIX;
      int cb = (x0 - 4 + 4 * sp) & 127;  // mult of 4 -> float4 aligned, wrap-safe
      float Ra[8], Rb[8], Rc[8];

#define LOADROW(dst, ry) { \
    const float* rp_ = yfp + (((ry) & 127) << 7); \
    float4 q0_ = *(const float4*)(rp_ + cb); \
    float4 q1_ = *(const float4*)(rp_ + ((cb + 4) & 127)); \
    dst[0]=q0_.x; dst[1]=q0_.y; dst[2]=q0_.z; dst[3]=q0_.w; \
    dst[4]=q1_.x; dst[5]=q1_.y; dst[6]=q1_.z; dst[7]=q1_.w; }

#define EMIT(rrw, R2_, R1_, R0_, CHK) { \
    int y_ = Ybase + (rrw); \
    _Pragma("unroll") \
    for (int j = 0; j < 4; ++j) { \
      int cidx_ = 4 * sp + j; \
      if (cidx_ < 18) { \
        float v_ = W0 * R0_[j + 3] + W1 * R0_[j + 2] + W2 * R0_[j + 1] \
                 + W3 * R1_[j + 3] + W4 * R1_[j + 2] + W5 * R1_[j + 1] \
                 + W6 * R2_[j + 3] + W7 * R2_[j + 2] + W8 * R2_[j + 1]; \
        if (CHK) { \
          int xg_ = x0 - 1 + cidx_; \
          if (!((y_ >= 0) && (y_ < 128) && (xg_ >= 0) && (xg_ < 128))) v_ = 0.f; \
        } \
        XFw[((rrw) * 18 + cidx_) * XFP + i] = (short)f2bf(v_); \
      } } }

#define PH1LOOP(CHK) { \
    LOADROW(Ra, Ybase - 2) \
    LOADROW(Rb, Ybase - 1) \
    LOADROW(Rc, Ybase)      EMIT(0, Ra, Rb, Rc, CHK) \
    LOADROW(Ra, Ybase + 1)  EMIT(1, Rb, Rc, Ra, CHK) \
    LOADROW(Rb, Ybase + 2)  EMIT(2, Rc, Ra, Rb, CHK) \
    LOADROW(Rc, Ybase + 3)  EMIT(3, Ra, Rb, Rc, CHK) \
    LOADROW(Ra, Ybase + 4)  EMIT(4, Rb, Rc, Ra, CHK) \
    LOADROW(Rb, Ybase + 5)  EMIT(5, Rc, Ra, Rb, CHK) }

      if (inter) PH1LOOP(0) else PH1LOOP(1)

#undef LOADROW
#undef EMIT
#undef PH1LOOP
    }
  }

  // phase 2 (per wave, no barrier): MFMA GEMM from the wave's own slice.
  int tx = lane & 15, gq = lane >> 4;
  f32x4 acc[4][3];
#pragma unroll
  for (int nn = 0; nn < 4; ++nn)
#pragma unroll
    for (int m = 0; m < 3; ++m) acc[nn][m] = (f32x4){0.f, 0.f, 0.f, 0.f};

  const unsigned short* abase = wbf64 + (tx)*64;
  bf16x8 Ac0[3], Ac1[3], An0[3], An1[3];
#pragma unroll
  for (int m = 0; m < 3; ++m) {
    const unsigned short* ap = abase + (m * 16) * 64;
    Ac0[m] = *(const bf16x8*)(ap + gq * 8);
    Ac1[m] = *(const bf16x8*)(ap + 32 + gq * 8);
  }

  for (int k = 0; k < 9; ++k) {
    if (k < 8) {
#pragma unroll
      for (int m = 0; m < 3; ++m) {
        const unsigned short* ap = abase + ((k + 1) * 48 + m * 16) * 64;
        An0[m] = *(const bf16x8*)(ap + gq * 8);
        An1[m] = *(const bf16x8*)(ap + 32 + gq * 8);
      }
    }
    int dy = k / 3, dx = k - dy * 3;
#pragma unroll
    for (int nn = 0; nn < 4; ++nn) {
      const short* bp = XFw + ((nn + dy) * 18 + tx + dx) * XFP;  // rrw = nn+dy in 0..5
      bf16x8 B0 = *(const bf16x8*)(bp + gq * 8);
      bf16x8 B1 = *(const bf16x8*)(bp + 32 + gq * 8);  // pad/next-row/tail, A=0 there
#pragma unroll
      for (int m = 0; m < 3; ++m) {
        acc[nn][m] = __builtin_amdgcn_mfma_f32_16x16x32_bf16(Ac0[m], B0, acc[nn][m], 0, 0, 0);
        acc[nn][m] = __builtin_amdgcn_mfma_f32_16x16x32_bf16(Ac1[m], B1, acc[nn][m], 0, 0, 0);
      }
    }
#pragma unroll
    for (int m = 0; m < 3; ++m) { Ac0[m] = An0[m]; Ac1[m] = An1[m]; }
  }

  // epilogue: C frag col=lane&15 (pixel x), row=gq*4+r (oc); y = y0+wv*4+nn
#pragma unroll
  for (int nn = 0; nn < 4; ++nn) {
    int y = y0 + wv * 4 + nn;
#pragma unroll
    for (int m = 0; m < 3; ++m) {
#pragma unroll
      for (int r = 0; r < 4; ++r) {
        int oc = m * 16 + gq * 4 + r;
        out[((size_t)(o * COUT + oc) << 14) + (y << 7) + x0 + tx] = acc[nn][m][r];
      }
    }
  }
}

// ---------------------------------------------------------------------------
extern "C" void kernel_launch(void* const* d_in, const int* in_sizes, int n_in,
                              void* d_out, int out_size, void* d_ws, size_t ws_size,
                              hipStream_t stream)
{
  const float* x      = (const float*)d_in[0];
  const float* freq   = (const float*)d_in[1];
  const float* theta  = (const float*)d_in[2];
  const float* sigma  = (const float*)d_in[3];
  const float* psi    = (const float*)d_in[4];
  const float* f0     = (const float*)d_in[5];
  const float* theta0 = (const float*)d_in[6];
  float* out = (float*)d_out;
  float* ws  = (float*)d_ws;

  float*  w     = ws;
  float*  ar    = ws + 20736;
  float*  ai    = ws + 20864;
  float2* Up    = (float2*)(ws + OFF_UP);
  float*  yf    = ws + OFF_YF;
  unsigned short* wbf64 = (unsigned short*)(ws + OFF_WBF64);

  gabor_k<<<dim3(81), dim3(256), 0, stream>>>(freq, theta, sigma, psi, f0, theta0, w, wbf64);
  circ_k<<<dim3(1), dim3(128), 0, stream>>>(ar, ai);
  stage1_k<<<dim3(16, 48), dim3(256), 0, stream>>>(x, ar, ai, Up);
  stage2_k<<<dim3(16, 48), dim3(256), 0, stream>>>(Up, ar, ai, yf);
  conv2_k<<<dim3(8, 8, 48), dim3(256), 0, stream>>>(yf, w, wbf64, out);
}